// Round 17
// baseline (182.412 us; speedup 1.0000x reference)
//
#include <hip/hip_runtime.h>
#include <hip/hip_bf16.h>
#include <cstdint>

using bf16x8 = __attribute__((ext_vector_type(8))) short;
using f32x4  = __attribute__((ext_vector_type(4))) float;
using bf16_t = __hip_bfloat16;

#define DEVI static __device__ __forceinline__

constexpr int kB = 4, kC = 256, kNH = 8, kDh = 32;
constexpr int kVP = 6, kVW = 16, kHP = 32, kHW = 3;
constexpr int kNW = 48, kP = 192, kGRID = 96;
constexpr int kRows = kB * kNW * kP;    // 36864
constexpr int kFF = 1024;
constexpr float kScale = 0.0625f;       // 1/sqrt(C)

DEVI void row_coords(int row, int& b, int& g1, int& g2) {
  int b_  = row / (kNW * kP);
  int rem = row - b_ * (kNW * kP);
  int w = rem / kP;
  int p = rem - w * kP;
  int vw = w / kHW, hw = w - vw * kHW;
  int vp = p >> 5,  hp = p & 31;
  int r  = vp * kVW + vw;
  int cc = hp * kHW + hw;
  g1 = r + 80;  if (g1 >= kGRID) g1 -= kGRID;
  g2 = cc + 93; if (g2 >= kGRID) g2 -= kGRID;
  b = b_;
}

DEVI float bf2f(short s) {
  union { unsigned u; float f; } c;
  c.u = ((unsigned)(unsigned short)s) << 16;
  return c.f;
}
DEVI short f2bf(float f) {
  bf16_t h = __float2bfloat16(f);
  return *reinterpret_cast<short*>(&h);
}

DEVI void gload16(const void* g, void* l) {
  __builtin_amdgcn_global_load_lds(
      (__attribute__((address_space(1))) void*)(uintptr_t)g,
      (__attribute__((address_space(3))) void*)(uintptr_t)l, 16, 0, 0);
}

// asm ds_read_b128: opaque to SIInsertWaitcnts so no compiler vmcnt(0) drain
// attaches to it — makes the counted vmcnt below real (R12: verified -17%).
DEVI bf16x8 ds_read_b128(uint32_t byte_off) {
  bf16x8 v;
  asm volatile("ds_read_b128 %0, %1" : "=v"(v) : "v"(byte_off));
  return v;
}

DEVI float gelu_fast(float v) {
  // sigmoid form of tanh-GELU, cube-form poly, no clamp (R16-validated).
  const float t2 = v * fmaf(0.0713548162f, v * v, 1.5957691216f);  // 2t
  return v / (1.f + __expf(-t2));
}

// ---------------- weight convert
__global__ __launch_bounds__(256) void k_wconv(
    const float* __restrict__ wq, const float* __restrict__ wk,
    const float* __restrict__ wv, const float* __restrict__ w1,
    const float* __restrict__ w2, bf16_t* __restrict__ W) {
  const int i = blockIdx.x * 256 + threadIdx.x;
  if (i < 196608) {                       // WqkvT: n*256+k
    const int n = i >> 8, k = i & 255;
    const float* src = n < 256 ? wq : (n < 512 ? wk : wv);
    W[i] = __float2bfloat16(src[k * 256 + (n & 255)]);
  } else if (i < 458752) {                // W1T: n*256+k, n<1024
    const int j = i - 196608;
    const int n = j >> 8, k = j & 255;
    W[i] = __float2bfloat16(w1[k * 1024 + n]);
  } else if (i < 720896) {                // W2T: n*1024+k, n<256
    const int j = i - 458752;
    const int n = j >> 10, k = j & 1023;
    W[i] = __float2bfloat16(w2[k * 256 + n]);
  }
}

// ---------------- gather + LN1 -> Y bf16
__global__ __launch_bounds__(256) void k_ln1(const float* __restrict__ emb,
    const float* __restrict__ gam, const float* __restrict__ bet,
    bf16_t* __restrict__ Y) {
  const int wave = threadIdx.x >> 6, lane = threadIdx.x & 63;
  #pragma unroll
  for (int rr = 0; rr < 2; ++rr) {
    const int row = blockIdx.x * 8 + wave * 2 + rr;
    int b, g1, g2; row_coords(row, b, g1, g2);
    const float* src = emb + (((size_t)b * kGRID + g1) * kGRID + g2) * kC;
    float4 x = *reinterpret_cast<const float4*>(src + lane * 4);
    float s  = x.x + x.y + x.z + x.w;
    float sq = x.x*x.x + x.y*x.y + x.z*x.z + x.w*x.w;
    #pragma unroll
    for (int off = 32; off; off >>= 1) { s += __shfl_xor(s, off); sq += __shfl_xor(sq, off); }
    const float mean = s * (1.f / kC);
    const float rstd = rsqrtf(sq * (1.f / kC) - mean * mean + 1e-5f);
    const float4 g4 = *reinterpret_cast<const float4*>(gam + lane * 4);
    const float4 b4 = *reinterpret_cast<const float4*>(bet + lane * 4);
    short4 o;
    o.x = f2bf((x.x - mean) * rstd * g4.x + b4.x);
    o.y = f2bf((x.y - mean) * rstd * g4.y + b4.y);
    o.z = f2bf((x.z - mean) * rstd * g4.z + b4.z);
    o.w = f2bf((x.w - mean) * rstd * g4.w + b4.w);
    *reinterpret_cast<short4*>(Y + (size_t)row * kC + lane * 4) = o;
  }
}

// ---------------- re-gather + residual + LN2 -> A bf16 (carry), H bf16
__global__ __launch_bounds__(256) void k_ln2(const float* __restrict__ emb,
    const bf16_t* __restrict__ SA,
    const float* __restrict__ gam, const float* __restrict__ bet,
    bf16_t* __restrict__ A, bf16_t* __restrict__ H) {
  const int wave = threadIdx.x >> 6, lane = threadIdx.x & 63;
  #pragma unroll
  for (int rr = 0; rr < 2; ++rr) {
    const int row = blockIdx.x * 8 + wave * 2 + rr;
    int b, g1, g2; row_coords(row, b, g1, g2);
    const float* src = emb + (((size_t)b * kGRID + g1) * kGRID + g2) * kC;
    float4 x = *reinterpret_cast<const float4*>(src + lane * 4);
    short4 sv = *reinterpret_cast<const short4*>(SA + (size_t)row * kC + lane * 4);
    x.x += bf2f(sv.x); x.y += bf2f(sv.y); x.z += bf2f(sv.z); x.w += bf2f(sv.w);
    short4 av;
    av.x = f2bf(x.x); av.y = f2bf(x.y); av.z = f2bf(x.z); av.w = f2bf(x.w);
    *reinterpret_cast<short4*>(A + (size_t)row * kC + lane * 4) = av;
    float s  = x.x + x.y + x.z + x.w;
    float sq = x.x*x.x + x.y*x.y + x.z*x.z + x.w*x.w;
    #pragma unroll
    for (int off = 32; off; off >>= 1) { s += __shfl_xor(s, off); sq += __shfl_xor(sq, off); }
    const float mean = s * (1.f / kC);
    const float rstd = rsqrtf(sq * (1.f / kC) - mean * mean + 1e-5f);
    const float4 g4 = *reinterpret_cast<const float4*>(gam + lane * 4);
    const float4 b4 = *reinterpret_cast<const float4*>(bet + lane * 4);
    short4 o;
    o.x = f2bf((x.x - mean) * rstd * g4.x + b4.x);
    o.y = f2bf((x.y - mean) * rstd * g4.y + b4.y);
    o.z = f2bf((x.z - mean) * rstd * g4.z + b4.z);
    o.w = f2bf((x.w - mean) * rstd * g4.w + b4.w);
    *reinterpret_cast<short4*>(H + (size_t)row * kC + lane * 4) = o;
  }
}

// ---------------- k_gemm9: TM=2 shared-B GEMM. Block = 256x128 output
// (two 128-row m-tiles sharing one B n-panel). 4 waves (2x2 per tile); per
// K-step per wave: 12 ds_read (4 B + 4 A0 + 4 A1) -> 32 MFMA (B register-
// reused across tiles). R15 triple-buffer single-barrier counted-vmcnt
// pipeline, 6 gloads/wave/stage -> vmcnt(6). LDS 72 KB -> 2 blocks/CU.
// Swizzle (r>>1)&3 both sides (R15: conflicts 0).
template <int KDIM, int EPI, int GX>
__global__ __launch_bounds__(256, 2) void k_gemm9(
    const bf16_t* __restrict__ Amat, const bf16_t* __restrict__ BT,
    const float* __restrict__ bias0, const float* __restrict__ bias1,
    const float* __restrict__ bias2,
    bf16_t* __restrict__ Obf) {
  __shared__ short sm[36864];            // 72 KB: 3 bufs x (A0 8K|A1 8K|B 8K)B
  const int tid = threadIdx.x;
  const int wave = tid >> 6, lane = tid & 63;
  const int lr = lane & 15, kg4 = lane >> 4;
  const int nwg = (kRows / 256) * GX;
  const int wg = (blockIdx.x & 7) * (nwg >> 3) + (blockIdx.x >> 3);
  const int m0 = (wg / GX) * 256, n0 = (wg % GX) * 128;
  const int wm = (wave >> 1) * 64, wn = (wave & 1) * 64;
  const int srow = lane >> 2;
  const int scol = ((lane & 3) ^ ((srow >> 1) & 3)) << 3;

  auto stage = [&](int buf, int k0) {
    bf16_t* const base = (bf16_t*)&sm[buf * 12288];
    #pragma unroll
    for (int i = 0; i < 2; ++i) {
      const int c = wave * 2 + i;                    // chunk 0..7
      const int row = c * 16 + srow;
      gload16(Amat + (size_t)(m0 + row) * KDIM + k0 + scol, base + c * 512);
      gload16(Amat + (size_t)(m0 + 128 + row) * KDIM + k0 + scol,
              base + 4096 + c * 512);
      gload16(BT + (size_t)(n0 + row) * KDIM + k0 + scol, base + 8192 + c * 512);
    }
  };

  f32x4 acc0[4][4] = {}, acc1[4][4] = {};
  auto compute = [&](int buf) {
    const uint32_t base = (uint32_t)(uintptr_t)&sm[buf * 12288];
    bf16x8 bq[4], a0[4], a1[4];
    #pragma unroll
    for (int n = 0; n < 4; ++n) {
      const int r = wn + n * 16 + lr;
      bq[n] = ds_read_b128(base + 16384 + r * 64 + ((kg4 ^ ((r >> 1) & 3)) << 4));
    }
    #pragma unroll
    for (int m = 0; m < 4; ++m) {
      const int r = wm + m * 16 + lr;
      const uint32_t off = r * 64 + ((kg4 ^ ((r >> 1) & 3)) << 4);
      a0[m] = ds_read_b128(base + off);
      a1[m] = ds_read_b128(base + 8192 + off);
    }
    asm volatile("s_waitcnt lgkmcnt(0)" ::: "memory");
    __builtin_amdgcn_sched_barrier(0);               // rule #18
    __builtin_amdgcn_s_setprio(1);
    #pragma unroll
    for (int m = 0; m < 4; ++m)
      #pragma unroll
      for (int n = 0; n < 4; ++n)
        acc0[m][n] = __builtin_amdgcn_mfma_f32_16x16x32_bf16(a0[m], bq[n], acc0[m][n], 0, 0, 0);
    #pragma unroll
    for (int m = 0; m < 4; ++m)
      #pragma unroll
      for (int n = 0; n < 4; ++n)
        acc1[m][n] = __builtin_amdgcn_mfma_f32_16x16x32_bf16(a1[m], bq[n], acc1[m][n], 0, 0, 0);
    __builtin_amdgcn_s_setprio(0);
  };

  stage(0, 0);
  if (KDIM > 32) stage(1, 32);                       // depth-2 prologue
  constexpr int NT = KDIM / 32;
  #pragma unroll
  for (int t = 0; t < NT; ++t) {
    if (t + 1 < NT) {
      asm volatile("s_waitcnt vmcnt(6)" ::: "memory");  // own t-loads landed
    } else {
      asm volatile("s_waitcnt vmcnt(0)" ::: "memory");
    }
    __builtin_amdgcn_sched_barrier(0);
    __builtin_amdgcn_s_barrier();          // all waves: t landed, t-1 computed
    if (t + 2 < NT) stage((t + 2) % 3, (t + 2) * 32);
    compute(t % 3);
  }
  __builtin_amdgcn_s_barrier();            // compute done before LDS reuse
  __builtin_amdgcn_sched_barrier(0);

  // epilogue (R16 wide-store LDS transpose), run per m-tile; static acc refs.
  auto epi = [&](const f32x4 (&acc)[4][4], int mbase) {
    short* scr = &sm[wave * 4096];                   // 64x64 bf16 slice
    const int colbase = n0 + wn;
    const float* bp;
    int cb;
    if constexpr (EPI == 0) {
      const int which = colbase >> 8;
      bp = which == 0 ? bias0 : (which == 1 ? bias1 : bias2);
      cb = colbase & 255;
    } else { bp = bias0; cb = colbase; }
    #pragma unroll
    for (int m = 0; m < 4; ++m)
      #pragma unroll
      for (int n = 0; n < 4; ++n)
        #pragma unroll
        for (int r = 0; r < 4; ++r) {
          const int lrow = m * 16 + kg4 * 4 + r;
          const int lcol = n * 16 + lr;
          float v = acc[m][n][r] + bp[cb + lcol];
          if constexpr (EPI == 1) v = gelu_fast(v);
          scr[lrow * 64 + (lcol ^ (((lrow >> 2) & 3) << 4))] = f2bf(v);
        }
    const int rl = lane >> 3, cl = (lane & 7) * 8;
    bf16_t* const obase = (EPI == 0)
        ? Obf + (size_t)(colbase >> 8) * kRows * kC
        : Obf;
    const int ld = (EPI == 0) ? kC : kFF;
    #pragma unroll
    for (int p = 0; p < 8; ++p) {
      const int lrow = p * 8 + rl;
      bf16x8 v = *reinterpret_cast<const bf16x8*>(
          &scr[lrow * 64 + (cl ^ (((lrow >> 2) & 3) << 4))]);
      *reinterpret_cast<bf16x8*>(
          obase + (size_t)(mbase + wm + lrow) * ld + cb + cl) = v;
    }
  };
  epi(acc0, m0);
  epi(acc1, m0 + 128);
}

// ---------------- k_gemm8 (R15/R16): kept for FFN2 (K=1024, 32-step
// pipeline + fp32 scatter epilogue with bf16 residual).
template <int KDIM, int GX>
__global__ __launch_bounds__(256, 3) void k_gemm8(
    const bf16_t* __restrict__ Amat, const bf16_t* __restrict__ BT,
    const float* __restrict__ bias0, const bf16_t* __restrict__ Ares,
    float* __restrict__ Out) {
  __shared__ short sm[24576];            // 48 KB: A[3]|B[3] bufs, then scratch
  bf16_t* As[3] = {(bf16_t*)&sm[0], (bf16_t*)&sm[4096], (bf16_t*)&sm[8192]};
  bf16_t* Bs[3] = {(bf16_t*)&sm[12288], (bf16_t*)&sm[16384], (bf16_t*)&sm[20480]};
  const int tid = threadIdx.x;
  const int wave = tid >> 6, lane = tid & 63;
  const int lr = lane & 15, kg4 = lane >> 4;
  const int nwg = (kRows / 128) * GX;
  const int wg = (blockIdx.x & 7) * (nwg >> 3) + (blockIdx.x >> 3);
  const int m0 = (wg / GX) * 128, n0 = (wg % GX) * 128;
  const int wm = (wave >> 1) * 64, wn = (wave & 1) * 64;
  const int srow = lane >> 2;
  const int scol = ((lane & 3) ^ ((srow >> 1) & 3)) << 3;

  auto stage = [&](bf16_t* aDst, bf16_t* bDst, int k0) {
    #pragma unroll
    for (int i = 0; i < 2; ++i) {
      const int c = wave * 2 + i;
      const int row = c * 16 + srow;
      gload16(Amat + (size_t)(m0 + row) * KDIM + k0 + scol, aDst + c * 512);
      gload16(BT   + (size_t)(n0 + row) * KDIM + k0 + scol, bDst + c * 512);
    }
  };

  const uint32_t aOff[3] = {(uint32_t)(uintptr_t)As[0], (uint32_t)(uintptr_t)As[1],
                            (uint32_t)(uintptr_t)As[2]};
  const uint32_t bOff[3] = {(uint32_t)(uintptr_t)Bs[0], (uint32_t)(uintptr_t)Bs[1],
                            (uint32_t)(uintptr_t)Bs[2]};

  f32x4 acc[4][4] = {};
  auto compute = [&](uint32_t aBase, uint32_t bBase) {
    bf16x8 af[4], bq[4];
    #pragma unroll
    for (int m = 0; m < 4; ++m) {
      const int r = wm + m * 16 + lr;
      af[m] = ds_read_b128(aBase + r * 64 + ((kg4 ^ ((r >> 1) & 3)) << 4));
    }
    #pragma unroll
    for (int n = 0; n < 4; ++n) {
      const int r = wn + n * 16 + lr;
      bq[n] = ds_read_b128(bBase + r * 64 + ((kg4 ^ ((r >> 1) & 3)) << 4));
    }
    asm volatile("s_waitcnt lgkmcnt(0)" ::: "memory");
    __builtin_amdgcn_sched_barrier(0);
    __builtin_amdgcn_s_setprio(1);
    #pragma unroll
    for (int m = 0; m < 4; ++m)
      #pragma unroll
      for (int n = 0; n < 4; ++n)
        acc[m][n] = __builtin_amdgcn_mfma_f32_16x16x32_bf16(af[m], bq[n], acc[m][n], 0, 0, 0);
    __builtin_amdgcn_s_setprio(0);
  };

  stage(As[0], Bs[0], 0);
  stage(As[1], Bs[1], 32);
  constexpr int NT = KDIM / 32;
  #pragma unroll
  for (int t = 0; t < NT; ++t) {
    if (t + 1 < NT) {
      asm volatile("s_waitcnt vmcnt(4)" ::: "memory");
    } else {
      asm volatile("s_waitcnt vmcnt(0)" ::: "memory");
    }
    __builtin_amdgcn_sched_barrier(0);
    __builtin_amdgcn_s_barrier();
    if (t + 2 < NT)
      stage(As[(t + 2) % 3], Bs[(t + 2) % 3], (t + 2) * 32);
    compute(aOff[t % 3], bOff[t % 3]);
  }
  __builtin_amdgcn_s_barrier();
  __builtin_amdgcn_sched_barrier(0);

  float* scrf = reinterpret_cast<float*>(&sm[wave * 4096]);  // 64x32 f32
  #pragma unroll
  for (int h = 0; h < 2; ++h) {
    #pragma unroll
    for (int m = 0; m < 4; ++m)
      #pragma unroll
      for (int nn = 0; nn < 2; ++nn) {
        const int n = h * 2 + nn;
        #pragma unroll
        for (int r = 0; r < 4; ++r) {
          const int lrow = m * 16 + kg4 * 4 + r;
          const int lcol = nn * 16 + lr;
          scrf[lrow * 32 + (lcol ^ (((lrow >> 2) & 3) << 3))] =
              acc[m][n][r] + bias0[n0 + wn + n * 16 + lr];
        }
      }
    const int rl = lane >> 3, cl = (lane & 7) * 4;
    #pragma unroll
    for (int p = 0; p < 8; ++p) {
      const int lrow = p * 8 + rl;
      const int row = m0 + wm + lrow;
      const int col = n0 + wn + h * 32 + cl;
      float4 v = *reinterpret_cast<const float4*>(
          &scrf[lrow * 32 + (cl ^ (((lrow >> 2) & 3) << 3))]);
      const short4 a4 = *reinterpret_cast<const short4*>(
          &Ares[(size_t)row * kC + col]);
      v.x += bf2f(a4.x); v.y += bf2f(a4.y);
      v.z += bf2f(a4.z); v.w += bf2f(a4.w);
      int b, g1, g2; row_coords(row, b, g1, g2);
      *reinterpret_cast<float4*>(
          &Out[(((size_t)b * kGRID + g1) * kGRID + g2) * kC + col]) = v;
    }
    if (h == 0) __builtin_amdgcn_s_barrier();
  }
}

// ---------------- MFMA attention (R11-R16, unchanged)
constexpr int kKsPad = 40;
constexpr int kVtPad = 200;
constexpr int kPlPad = 200;
__global__ __launch_bounds__(256) void k_attn(
    const bf16_t* __restrict__ Q, const bf16_t* __restrict__ K,
    const bf16_t* __restrict__ V, const float* __restrict__ pos,
    bf16_t* __restrict__ SA) {
  __shared__ short Ks[kP * kKsPad];
  __shared__ short Vt[kDh * kVtPad];
  __shared__ short Pl[4 * 16 * kPlPad];
  const int bw = blockIdx.x >> 3, h = blockIdx.x & 7;
  const int rowbase = bw * kP, colbase = h * kDh;
  const int tid = threadIdx.x, wave = tid >> 6, lane = tid & 63;
  const int lr = lane & 15, kg = lane >> 4;
  const int wq0 = wave * 48;
  const float* pb = pos + (size_t)h * kP * kP;

  #pragma unroll
  for (int i = 0; i < 3; ++i) {
    const int c = tid + i * 256;
    const int row = c >> 2, dch = (c & 3) * 8;
    const size_t gbase = (size_t)(rowbase + row) * kC + colbase + dch;
    bf16x8 kv = *reinterpret_cast<const bf16x8*>(K + gbase);
    *reinterpret_cast<bf16x8*>(&Ks[row * kKsPad + dch]) = kv;
    bf16x8 vv = *reinterpret_cast<const bf16x8*>(V + gbase);
    #pragma unroll
    for (int e = 0; e < 8; ++e) Vt[(dch + e) * kVtPad + row] = vv[e];
  }
  __syncthreads();

  for (int m = 0; m < 3; ++m) {
    const int rbase = wq0 + m * 16;
    bf16x8 aq = *reinterpret_cast<const bf16x8*>(
        Q + (size_t)(rowbase + rbase + lr) * kC + colbase + kg * 8);
    f32x4 s[12];
    #pragma unroll
    for (int n = 0; n < 12; ++n) {
      bf16x8 bk = *reinterpret_cast<const bf16x8*>(&Ks[(n * 16 + lr) * kKsPad + kg * 8]);
      s[n] = __builtin_amdgcn_mfma_f32_16x16x32_bf16(aq, bk, (f32x4){0.f, 0.f, 0.f, 0.f}, 0, 0, 0);
    }
    float mx[4] = {-1e30f, -1e30f, -1e30f, -1e30f};
    #pragma unroll
    for (int n = 0; n < 12; ++n) {
      #pragma unroll
      for (int r = 0; r < 4; ++r) {
        const float lg = fmaf(s[n][r], kScale,
                              pb[(size_t)(rbase + kg * 4 + r) * kP + n * 16 + lr]);
        s[n][r] = lg;
        mx[r] = fmaxf(mx[r], lg);
      }
    }
    #pragma unroll
    for (int r = 0; r < 4; ++r)
      #pragma unroll
      for (int off = 8; off; off >>= 1) mx[r] = fmaxf(mx[r], __shfl_xor(mx[r], off));
    float sm4[4] = {0.f, 0.f, 0.f, 0.f};
    #pragma unroll
    for (int n = 0; n < 12; ++n)
      #pragma unroll
      for (int r = 0; r < 4; ++r) {
        const float e = __expf(s[n][r] - mx[r]);
        s[n][r] = e;
        sm4[r] += e;
      }
    #pragma unroll
    for (int r = 0; r < 4; ++r) {
      #pragma unroll
      for (int off = 8; off; off >>= 1) sm4[r] += __shfl_xor(sm4[r], off);
      sm4[r] = 1.f / sm4[r];
    }
    #pragma unroll
    for (int n = 0; n < 12; ++n)
      #pragma unroll
      for (int r = 0; r < 4; ++r)
        Pl[(wave * 16 + kg * 4 + r) * kPlPad + n * 16 + lr] = f2bf(s[n][r] * sm4[r]);
    f32x4 o0 = {0.f, 0.f, 0.f, 0.f}, o1 = {0.f, 0.f, 0.f, 0.f};
    #pragma unroll
    for (int kk = 0; kk < 6; ++kk) {
      bf16x8 ap = *reinterpret_cast<const bf16x8*>(&Pl[(wave * 16 + lr) * kPlPad + kk * 32 + kg * 8]);
      bf16x8 b0 = *reinterpret_cast<const bf16x8*>(&Vt[lr * kVtPad + kk * 32 + kg * 8]);
      bf16x8 b1 = *reinterpret_cast<const bf16x8*>(&Vt[(16 + lr) * kVtPad + kk * 32 + kg * 8]);
      o0 = __builtin_amdgcn_mfma_f32_16x16x32_bf16(ap, b0, o0, 0, 0, 0);
      o1 = __builtin_amdgcn_mfma_f32_16x16x32_bf16(ap, b1, o1, 0, 0, 0);
    }
    short* scr2 = &Pl[wave * 16 * kPlPad];
    #pragma unroll
    for (int r = 0; r < 4; ++r) {
      scr2[(kg * 4 + r) * 32 + lr]      = f2bf(o0[r]);
      scr2[(kg * 4 + r) * 32 + 16 + lr] = f2bf(o1[r]);
    }
    {
      const int rrow = lane >> 2, c0 = (lane & 3) * 8;
      bf16x8 v = *reinterpret_cast<const bf16x8*>(&scr2[rrow * 32 + c0]);
      *reinterpret_cast<bf16x8*>(
          SA + (size_t)(rowbase + rbase + rrow) * kC + colbase + c0) = v;
    }
  }
}

extern "C" void kernel_launch(void* const* d_in, const int* in_sizes, int n_in,
                              void* d_out, int out_size, void* d_ws, size_t ws_size,
                              hipStream_t stream) {
  const float* emb  = (const float*)d_in[0];
  const float* ln1g = (const float*)d_in[1];
  const float* ln1b = (const float*)d_in[2];
  const float* wq   = (const float*)d_in[3];
  const float* bq   = (const float*)d_in[4];
  const float* wk   = (const float*)d_in[5];
  const float* bk   = (const float*)d_in[6];
  const float* wv   = (const float*)d_in[7];
  const float* bv   = (const float*)d_in[8];
  const float* pos  = (const float*)d_in[9];
  const float* ln2g = (const float*)d_in[10];
  const float* ln2b = (const float*)d_in[11];
  const float* w1   = (const float*)d_in[12];
  const float* b1   = (const float*)d_in[13];
  const float* w2   = (const float*)d_in[14];
  const float* b2   = (const float*)d_in[15];

  char* ws = (char*)d_ws;
  const size_t nYb = (size_t)kRows * kC * 2;               // 18,874,368 B
  bf16_t* Y    = (bf16_t*)(ws);
  bf16_t* Qb   = (bf16_t*)(ws + nYb);                      // Q,K,V consecutive
  bf16_t* SAb  = (bf16_t*)(ws + nYb * 4);
  bf16_t* Abuf = (bf16_t*)(ws + nYb * 5);                  // bf16 carry
  bf16_t* H    = (bf16_t*)(ws + nYb * 5 + (size_t)kRows * kC * 4);
  bf16_t* G    = (bf16_t*)(ws);                            // alias dead Y/Q/K/V
  bf16_t* W    = (bf16_t*)(ws + nYb * 5 + (size_t)kRows * kC * 4 + nYb);
  bf16_t* WqkvT = W;
  bf16_t* W1T   = W + 768 * 256;
  bf16_t* W2T   = W1T + 1024 * 256;

  k_wconv<<<2816, 256, 0, stream>>>(wq, wk, wv, w1, w2, W);
  k_ln1<<<kRows / 8, 256, 0, stream>>>(emb, ln1g, ln1b, Y);
  k_gemm9<256, 0, 6><<<(kRows / 256) * 6, 256, 0, stream>>>(
      Y, WqkvT, bq, bk, bv, Qb);
  k_attn<<<kB * kNW * kNH, 256, 0, stream>>>(
      Qb, Qb + (size_t)kRows * kC, Qb + 2 * (size_t)kRows * kC, pos, SAb);
  k_ln2<<<kRows / 8, 256, 0, stream>>>(emb, SAb, ln2g, ln2b, Abuf, H);
  k_gemm9<256, 1, 8><<<(kRows / 256) * 8, 256, 0, stream>>>(
      H, W1T, b1, nullptr, nullptr, G);
  k_gemm8<1024, 2><<<(kRows / 128) * 2, 256, 0, stream>>>(
      G, W2T, b2, Abuf, (float*)d_out);
}

// Round 18
// 169.446 us; speedup vs baseline: 1.0765x; 1.0765x over previous
//
#include <hip/hip_runtime.h>
#include <hip/hip_bf16.h>
#include <cstdint>

using bf16x8 = __attribute__((ext_vector_type(8))) short;
using f32x4  = __attribute__((ext_vector_type(4))) float;
using bf16_t = __hip_bfloat16;

#define DEVI static __device__ __forceinline__

constexpr int kB = 4, kC = 256, kNH = 8, kDh = 32;
constexpr int kVP = 6, kVW = 16, kHP = 32, kHW = 3;
constexpr int kNW = 48, kP = 192, kGRID = 96;
constexpr int kRows = kB * kNW * kP;    // 36864
constexpr int kFF = 1024;
constexpr float kScale = 0.0625f;       // 1/sqrt(C)

DEVI void row_coords(int row, int& b, int& g1, int& g2) {
  int b_  = row / (kNW * kP);
  int rem = row - b_ * (kNW * kP);
  int w = rem / kP;
  int p = rem - w * kP;
  int vw = w / kHW, hw = w - vw * kHW;
  int vp = p >> 5,  hp = p & 31;
  int r  = vp * kVW + vw;
  int cc = hp * kHW + hw;
  g1 = r + 80;  if (g1 >= kGRID) g1 -= kGRID;
  g2 = cc + 93; if (g2 >= kGRID) g2 -= kGRID;
  b = b_;
}

DEVI float bf2f(short s) {
  union { unsigned u; float f; } c;
  c.u = ((unsigned)(unsigned short)s) << 16;
  return c.f;
}
DEVI short f2bf(float f) {
  bf16_t h = __float2bfloat16(f);
  return *reinterpret_cast<short*>(&h);
}

DEVI void gload16(const void* g, void* l) {
  __builtin_amdgcn_global_load_lds(
      (__attribute__((address_space(1))) void*)(uintptr_t)g,
      (__attribute__((address_space(3))) void*)(uintptr_t)l, 16, 0, 0);
}

// asm ds_read_b128: opaque to SIInsertWaitcnts so no compiler vmcnt(0) drain
// attaches to it — makes the counted vmcnt below real (R12: verified -17%).
DEVI bf16x8 ds_read_b128(uint32_t byte_off) {
  bf16x8 v;
  asm volatile("ds_read_b128 %0, %1" : "=v"(v) : "v"(byte_off));
  return v;
}

DEVI float gelu_fast(float v) {
  // sigmoid approximation v*sigma(1.702v); |err| vs exact <= 0.02 worst-case,
  // <<1e-3 in the preact range here (sigma~0.32). Saves the cubic poly.
  return v / (1.f + __expf(-1.702f * v));
}

// ---------------- weight convert
__global__ __launch_bounds__(256) void k_wconv(
    const float* __restrict__ wq, const float* __restrict__ wk,
    const float* __restrict__ wv, const float* __restrict__ w1,
    const float* __restrict__ w2, bf16_t* __restrict__ W) {
  const int i = blockIdx.x * 256 + threadIdx.x;
  if (i < 196608) {                       // WqkvT: n*256+k
    const int n = i >> 8, k = i & 255;
    const float* src = n < 256 ? wq : (n < 512 ? wk : wv);
    W[i] = __float2bfloat16(src[k * 256 + (n & 255)]);
  } else if (i < 458752) {                // W1T: n*256+k, n<1024
    const int j = i - 196608;
    const int n = j >> 8, k = j & 255;
    W[i] = __float2bfloat16(w1[k * 1024 + n]);
  } else if (i < 720896) {                // W2T: n*1024+k, n<256
    const int j = i - 458752;
    const int n = j >> 10, k = j & 1023;
    W[i] = __float2bfloat16(w2[k * 256 + n]);
  }
}

// ---------------- gather + LN1 -> Y bf16
__global__ __launch_bounds__(256) void k_ln1(const float* __restrict__ emb,
    const float* __restrict__ gam, const float* __restrict__ bet,
    bf16_t* __restrict__ Y) {
  const int wave = threadIdx.x >> 6, lane = threadIdx.x & 63;
  #pragma unroll
  for (int rr = 0; rr < 2; ++rr) {
    const int row = blockIdx.x * 8 + wave * 2 + rr;
    int b, g1, g2; row_coords(row, b, g1, g2);
    const float* src = emb + (((size_t)b * kGRID + g1) * kGRID + g2) * kC;
    float4 x = *reinterpret_cast<const float4*>(src + lane * 4);
    float s  = x.x + x.y + x.z + x.w;
    float sq = x.x*x.x + x.y*x.y + x.z*x.z + x.w*x.w;
    #pragma unroll
    for (int off = 32; off; off >>= 1) { s += __shfl_xor(s, off); sq += __shfl_xor(sq, off); }
    const float mean = s * (1.f / kC);
    const float rstd = rsqrtf(sq * (1.f / kC) - mean * mean + 1e-5f);
    const float4 g4 = *reinterpret_cast<const float4*>(gam + lane * 4);
    const float4 b4 = *reinterpret_cast<const float4*>(bet + lane * 4);
    short4 o;
    o.x = f2bf((x.x - mean) * rstd * g4.x + b4.x);
    o.y = f2bf((x.y - mean) * rstd * g4.y + b4.y);
    o.z = f2bf((x.z - mean) * rstd * g4.z + b4.z);
    o.w = f2bf((x.w - mean) * rstd * g4.w + b4.w);
    *reinterpret_cast<short4*>(Y + (size_t)row * kC + lane * 4) = o;
  }
}

// ---------------- re-gather + residual + LN2 -> A bf16 (carry), H bf16
__global__ __launch_bounds__(256) void k_ln2(const float* __restrict__ emb,
    const bf16_t* __restrict__ SA,
    const float* __restrict__ gam, const float* __restrict__ bet,
    bf16_t* __restrict__ A, bf16_t* __restrict__ H) {
  const int wave = threadIdx.x >> 6, lane = threadIdx.x & 63;
  #pragma unroll
  for (int rr = 0; rr < 2; ++rr) {
    const int row = blockIdx.x * 8 + wave * 2 + rr;
    int b, g1, g2; row_coords(row, b, g1, g2);
    const float* src = emb + (((size_t)b * kGRID + g1) * kGRID + g2) * kC;
    float4 x = *reinterpret_cast<const float4*>(src + lane * 4);
    short4 sv = *reinterpret_cast<const short4*>(SA + (size_t)row * kC + lane * 4);
    x.x += bf2f(sv.x); x.y += bf2f(sv.y); x.z += bf2f(sv.z); x.w += bf2f(sv.w);
    short4 av;
    av.x = f2bf(x.x); av.y = f2bf(x.y); av.z = f2bf(x.z); av.w = f2bf(x.w);
    *reinterpret_cast<short4*>(A + (size_t)row * kC + lane * 4) = av;
    float s  = x.x + x.y + x.z + x.w;
    float sq = x.x*x.x + x.y*x.y + x.z*x.z + x.w*x.w;
    #pragma unroll
    for (int off = 32; off; off >>= 1) { s += __shfl_xor(s, off); sq += __shfl_xor(sq, off); }
    const float mean = s * (1.f / kC);
    const float rstd = rsqrtf(sq * (1.f / kC) - mean * mean + 1e-5f);
    const float4 g4 = *reinterpret_cast<const float4*>(gam + lane * 4);
    const float4 b4 = *reinterpret_cast<const float4*>(bet + lane * 4);
    short4 o;
    o.x = f2bf((x.x - mean) * rstd * g4.x + b4.x);
    o.y = f2bf((x.y - mean) * rstd * g4.y + b4.y);
    o.z = f2bf((x.z - mean) * rstd * g4.z + b4.z);
    o.w = f2bf((x.w - mean) * rstd * g4.w + b4.w);
    *reinterpret_cast<short4*>(H + (size_t)row * kC + lane * 4) = o;
  }
}

// ---------------- k_gemm8 (R15/R16 best): 128x128 / BK=32 / 4 waves,
// triple-buffer single-barrier depth-2 counted-vmcnt pipeline, swizzle
// (r>>1)&3 both sides (R15: bank conflicts 3.8M -> 0).
template <int KDIM, int EPI, int GX>
__global__ __launch_bounds__(256, 3) void k_gemm8(
    const bf16_t* __restrict__ Amat, const bf16_t* __restrict__ BT,
    const float* __restrict__ bias0, const float* __restrict__ bias1,
    const float* __restrict__ bias2,
    bf16_t* __restrict__ Obf, const bf16_t* __restrict__ Ares,
    float* __restrict__ Out) {
  __shared__ short sm[24576];            // 48 KB: A[3]|B[3] bufs, then scratch
  bf16_t* As[3] = {(bf16_t*)&sm[0], (bf16_t*)&sm[4096], (bf16_t*)&sm[8192]};
  bf16_t* Bs[3] = {(bf16_t*)&sm[12288], (bf16_t*)&sm[16384], (bf16_t*)&sm[20480]};
  const int tid = threadIdx.x;
  const int wave = tid >> 6, lane = tid & 63;
  const int lr = lane & 15, kg4 = lane >> 4;         // k-group 0..3
  const int nwg = (kRows / 128) * GX;
  const int wg = (blockIdx.x & 7) * (nwg >> 3) + (blockIdx.x >> 3);
  const int m0 = (wg / GX) * 128, n0 = (wg % GX) * 128;
  const int wm = (wave >> 1) * 64, wn = (wave & 1) * 64;
  const int srow = lane >> 2;                        // row within 16-row chunk
  const int scol = ((lane & 3) ^ ((srow >> 1) & 3)) << 3;  // pre-swizzled slot

  auto stage = [&](bf16_t* aDst, bf16_t* bDst, int k0) {
    #pragma unroll
    for (int i = 0; i < 2; ++i) {
      const int c = wave * 2 + i;                    // chunk 0..7
      const int row = c * 16 + srow;
      gload16(Amat + (size_t)(m0 + row) * KDIM + k0 + scol, aDst + c * 512);
      gload16(BT   + (size_t)(n0 + row) * KDIM + k0 + scol, bDst + c * 512);
    }
  };

  const uint32_t aOff[3] = {(uint32_t)(uintptr_t)As[0], (uint32_t)(uintptr_t)As[1],
                            (uint32_t)(uintptr_t)As[2]};
  const uint32_t bOff[3] = {(uint32_t)(uintptr_t)Bs[0], (uint32_t)(uintptr_t)Bs[1],
                            (uint32_t)(uintptr_t)Bs[2]};

  f32x4 acc[4][4] = {};
  auto compute = [&](uint32_t aBase, uint32_t bBase) {
    bf16x8 af[4], bq[4];
    #pragma unroll
    for (int m = 0; m < 4; ++m) {
      const int r = wm + m * 16 + lr;
      af[m] = ds_read_b128(aBase + r * 64 + ((kg4 ^ ((r >> 1) & 3)) << 4));
    }
    #pragma unroll
    for (int n = 0; n < 4; ++n) {
      const int r = wn + n * 16 + lr;
      bq[n] = ds_read_b128(bBase + r * 64 + ((kg4 ^ ((r >> 1) & 3)) << 4));
    }
    asm volatile("s_waitcnt lgkmcnt(0)" ::: "memory");
    __builtin_amdgcn_sched_barrier(0);               // rule #18
    __builtin_amdgcn_s_setprio(1);
    #pragma unroll
    for (int m = 0; m < 4; ++m)
      #pragma unroll
      for (int n = 0; n < 4; ++n)
        acc[m][n] = __builtin_amdgcn_mfma_f32_16x16x32_bf16(af[m], bq[n], acc[m][n], 0, 0, 0);
    __builtin_amdgcn_s_setprio(0);
  };

  stage(As[0], Bs[0], 0);
  if (KDIM > 32) stage(As[1], Bs[1], 32);            // depth-2 prologue
  constexpr int NT = KDIM / 32;
  #pragma unroll
  for (int t = 0; t < NT; ++t) {
    if (t + 1 < NT) {
      asm volatile("s_waitcnt vmcnt(4)" ::: "memory");  // own t-loads landed
    } else {
      asm volatile("s_waitcnt vmcnt(0)" ::: "memory");
    }
    __builtin_amdgcn_sched_barrier(0);
    __builtin_amdgcn_s_barrier();          // all waves: t landed, t-1 computed
    if (t + 2 < NT)
      stage(As[(t + 2) % 3], Bs[(t + 2) % 3], (t + 2) * 32);
    compute(aOff[t % 3], bOff[t % 3]);
  }
  __builtin_amdgcn_s_barrier();            // compute done before LDS reuse
  __builtin_amdgcn_sched_barrier(0);

  if constexpr (EPI == 0 || EPI == 1) {
    short* scr = &sm[wave * 4096];                   // 64x64 bf16, rows 128B
    const int colbase = n0 + wn;
    const float* bp;
    int cb;
    if constexpr (EPI == 0) {
      const int which = colbase >> 8;
      bp = which == 0 ? bias0 : (which == 1 ? bias1 : bias2);
      cb = colbase & 255;
    } else { bp = bias0; cb = colbase; }
    #pragma unroll
    for (int m = 0; m < 4; ++m)
      #pragma unroll
      for (int n = 0; n < 4; ++n)
        #pragma unroll
        for (int r = 0; r < 4; ++r) {
          const int lrow = m * 16 + kg4 * 4 + r;
          const int lcol = n * 16 + lr;
          float v = acc[m][n][r] + bp[cb + lcol];
          if constexpr (EPI == 1) v = gelu_fast(v);
          scr[lrow * 64 + (lcol ^ (((lrow >> 2) & 3) << 4))] = f2bf(v);
        }
    const int rl = lane >> 3, cl = (lane & 7) * 8;   // 8 lanes/row, 16B/lane
    bf16_t* const obase = (EPI == 0)
        ? Obf + (size_t)(colbase >> 8) * kRows * kC
        : Obf;
    const int ld = (EPI == 0) ? kC : kFF;
    #pragma unroll
    for (int p = 0; p < 8; ++p) {
      const int lrow = p * 8 + rl;
      bf16x8 v = *reinterpret_cast<const bf16x8*>(
          &scr[lrow * 64 + (cl ^ (((lrow >> 2) & 3) << 4))]);
      *reinterpret_cast<bf16x8*>(
          obase + (size_t)(m0 + wm + lrow) * ld + cb + cl) = v;
    }
  } else {
    float* scrf = reinterpret_cast<float*>(&sm[wave * 4096]);  // 64x32 f32
    #pragma unroll
    for (int h = 0; h < 2; ++h) {
      #pragma unroll
      for (int m = 0; m < 4; ++m)
        #pragma unroll
        for (int nn = 0; nn < 2; ++nn) {
          const int n = h * 2 + nn;
          #pragma unroll
          for (int r = 0; r < 4; ++r) {
            const int lrow = m * 16 + kg4 * 4 + r;
            const int lcol = nn * 16 + lr;
            scrf[lrow * 32 + (lcol ^ (((lrow >> 2) & 3) << 3))] =
                acc[m][n][r] + bias0[n0 + wn + n * 16 + lr];
          }
        }
      const int rl = lane >> 3, cl = (lane & 7) * 4; // 8 lanes/row, 16B/lane
      #pragma unroll
      for (int p = 0; p < 8; ++p) {
        const int lrow = p * 8 + rl;
        const int row = m0 + wm + lrow;
        const int col = n0 + wn + h * 32 + cl;
        float4 v = *reinterpret_cast<const float4*>(
            &scrf[lrow * 32 + (cl ^ (((lrow >> 2) & 3) << 3))]);
        const short4 a4 = *reinterpret_cast<const short4*>(
            &Ares[(size_t)row * kC + col]);
        v.x += bf2f(a4.x); v.y += bf2f(a4.y);
        v.z += bf2f(a4.z); v.w += bf2f(a4.w);
        int b, g1, g2; row_coords(row, b, g1, g2);
        *reinterpret_cast<float4*>(
            &Out[(((size_t)b * kGRID + g1) * kGRID + g2) * kC + col]) = v;
      }
      if (h == 0) __builtin_amdgcn_s_barrier();      // keep waves in step
    }
  }
}

// ---------------- MFMA attention (R11-R16, unchanged)
constexpr int kKsPad = 40;
constexpr int kVtPad = 200;
constexpr int kPlPad = 200;
__global__ __launch_bounds__(256) void k_attn(
    const bf16_t* __restrict__ Q, const bf16_t* __restrict__ K,
    const bf16_t* __restrict__ V, const float* __restrict__ pos,
    bf16_t* __restrict__ SA) {
  __shared__ short Ks[kP * kKsPad];
  __shared__ short Vt[kDh * kVtPad];
  __shared__ short Pl[4 * 16 * kPlPad];
  const int bw = blockIdx.x >> 3, h = blockIdx.x & 7;
  const int rowbase = bw * kP, colbase = h * kDh;
  const int tid = threadIdx.x, wave = tid >> 6, lane = tid & 63;
  const int lr = lane & 15, kg = lane >> 4;
  const int wq0 = wave * 48;
  const float* pb = pos + (size_t)h * kP * kP;

  #pragma unroll
  for (int i = 0; i < 3; ++i) {
    const int c = tid + i * 256;
    const int row = c >> 2, dch = (c & 3) * 8;
    const size_t gbase = (size_t)(rowbase + row) * kC + colbase + dch;
    bf16x8 kv = *reinterpret_cast<const bf16x8*>(K + gbase);
    *reinterpret_cast<bf16x8*>(&Ks[row * kKsPad + dch]) = kv;
    bf16x8 vv = *reinterpret_cast<const bf16x8*>(V + gbase);
    #pragma unroll
    for (int e = 0; e < 8; ++e) Vt[(dch + e) * kVtPad + row] = vv[e];
  }
  __syncthreads();

  for (int m = 0; m < 3; ++m) {
    const int rbase = wq0 + m * 16;
    bf16x8 aq = *reinterpret_cast<const bf16x8*>(
        Q + (size_t)(rowbase + rbase + lr) * kC + colbase + kg * 8);
    f32x4 s[12];
    #pragma unroll
    for (int n = 0; n < 12; ++n) {
      bf16x8 bk = *reinterpret_cast<const bf16x8*>(&Ks[(n * 16 + lr) * kKsPad + kg * 8]);
      s[n] = __builtin_amdgcn_mfma_f32_16x16x32_bf16(aq, bk, (f32x4){0.f, 0.f, 0.f, 0.f}, 0, 0, 0);
    }
    float mx[4] = {-1e30f, -1e30f, -1e30f, -1e30f};
    #pragma unroll
    for (int n = 0; n < 12; ++n) {
      #pragma unroll
      for (int r = 0; r < 4; ++r) {
        const float lg = fmaf(s[n][r], kScale,
                              pb[(size_t)(rbase + kg * 4 + r) * kP + n * 16 + lr]);
        s[n][r] = lg;
        mx[r] = fmaxf(mx[r], lg);
      }
    }
    #pragma unroll
    for (int r = 0; r < 4; ++r)
      #pragma unroll
      for (int off = 8; off; off >>= 1) mx[r] = fmaxf(mx[r], __shfl_xor(mx[r], off));
    float sm4[4] = {0.f, 0.f, 0.f, 0.f};
    #pragma unroll
    for (int n = 0; n < 12; ++n)
      #pragma unroll
      for (int r = 0; r < 4; ++r) {
        const float e = __expf(s[n][r] - mx[r]);
        s[n][r] = e;
        sm4[r] += e;
      }
    #pragma unroll
    for (int r = 0; r < 4; ++r) {
      #pragma unroll
      for (int off = 8; off; off >>= 1) sm4[r] += __shfl_xor(sm4[r], off);
      sm4[r] = 1.f / sm4[r];
    }
    #pragma unroll
    for (int n = 0; n < 12; ++n)
      #pragma unroll
      for (int r = 0; r < 4; ++r)
        Pl[(wave * 16 + kg * 4 + r) * kPlPad + n * 16 + lr] = f2bf(s[n][r] * sm4[r]);
    f32x4 o0 = {0.f, 0.f, 0.f, 0.f}, o1 = {0.f, 0.f, 0.f, 0.f};
    #pragma unroll
    for (int kk = 0; kk < 6; ++kk) {
      bf16x8 ap = *reinterpret_cast<const bf16x8*>(&Pl[(wave * 16 + lr) * kPlPad + kk * 32 + kg * 8]);
      bf16x8 b0 = *reinterpret_cast<const bf16x8*>(&Vt[lr * kVtPad + kk * 32 + kg * 8]);
      bf16x8 b1 = *reinterpret_cast<const bf16x8*>(&Vt[(16 + lr) * kVtPad + kk * 32 + kg * 8]);
      o0 = __builtin_amdgcn_mfma_f32_16x16x32_bf16(ap, b0, o0, 0, 0, 0);
      o1 = __builtin_amdgcn_mfma_f32_16x16x32_bf16(ap, b1, o1, 0, 0, 0);
    }
    short* scr2 = &Pl[wave * 16 * kPlPad];
    #pragma unroll
    for (int r = 0; r < 4; ++r) {
      scr2[(kg * 4 + r) * 32 + lr]      = f2bf(o0[r]);
      scr2[(kg * 4 + r) * 32 + 16 + lr] = f2bf(o1[r]);
    }
    {
      const int rrow = lane >> 2, c0 = (lane & 3) * 8;
      bf16x8 v = *reinterpret_cast<const bf16x8*>(&scr2[rrow * 32 + c0]);
      *reinterpret_cast<bf16x8*>(
          SA + (size_t)(rowbase + rbase + rrow) * kC + colbase + c0) = v;
    }
  }
}

extern "C" void kernel_launch(void* const* d_in, const int* in_sizes, int n_in,
                              void* d_out, int out_size, void* d_ws, size_t ws_size,
                              hipStream_t stream) {
  const float* emb  = (const float*)d_in[0];
  const float* ln1g = (const float*)d_in[1];
  const float* ln1b = (const float*)d_in[2];
  const float* wq   = (const float*)d_in[3];
  const float* bq   = (const float*)d_in[4];
  const float* wk   = (const float*)d_in[5];
  const float* bk   = (const float*)d_in[6];
  const float* wv   = (const float*)d_in[7];
  const float* bv   = (const float*)d_in[8];
  const float* pos  = (const float*)d_in[9];
  const float* ln2g = (const float*)d_in[10];
  const float* ln2b = (const float*)d_in[11];
  const float* w1   = (const float*)d_in[12];
  const float* b1   = (const float*)d_in[13];
  const float* w2   = (const float*)d_in[14];
  const float* b2   = (const float*)d_in[15];

  char* ws = (char*)d_ws;
  const size_t nYb = (size_t)kRows * kC * 2;               // 18,874,368 B
  bf16_t* Y    = (bf16_t*)(ws);
  bf16_t* Qb   = (bf16_t*)(ws + nYb);                      // Q,K,V consecutive
  bf16_t* SAb  = (bf16_t*)(ws + nYb * 4);
  bf16_t* Abuf = (bf16_t*)(ws + nYb * 5);                  // bf16 carry
  bf16_t* H    = (bf16_t*)(ws + nYb * 5 + (size_t)kRows * kC * 4);
  bf16_t* G    = (bf16_t*)(ws);                            // alias dead Y/Q/K/V
  bf16_t* W    = (bf16_t*)(ws + nYb * 5 + (size_t)kRows * kC * 4 + nYb);
  bf16_t* WqkvT = W;
  bf16_t* W1T   = W + 768 * 256;
  bf16_t* W2T   = W1T + 1024 * 256;

  k_wconv<<<2816, 256, 0, stream>>>(wq, wk, wv, w1, w2, W);
  k_ln1<<<kRows / 8, 256, 0, stream>>>(emb, ln1g, ln1b, Y);
  k_gemm8<256, 0, 6><<<(kRows / 128) * 6, 256, 0, stream>>>(
      Y, WqkvT, bq, bk, bv, Qb, nullptr, nullptr);
  k_attn<<<kB * kNW * kNH, 256, 0, stream>>>(
      Qb, Qb + (size_t)kRows * kC, Qb + 2 * (size_t)kRows * kC, pos, SAb);
  k_ln2<<<kRows / 8, 256, 0, stream>>>(emb, SAb, ln2g, ln2b, Abuf, H);
  k_gemm8<256, 1, 8><<<(kRows / 128) * 8, 256, 0, stream>>>(
      H, W1T, b1, nullptr, nullptr, G, nullptr, nullptr);
  k_gemm8<1024, 2, 2><<<(kRows / 128) * 2, 256, 0, stream>>>(
      G, W2T, b2, nullptr, nullptr, nullptr, Abuf, (float*)d_out);
}

// Round 19
// 168.247 us; speedup vs baseline: 1.0842x; 1.0071x over previous
//
#include <hip/hip_runtime.h>
#include <hip/hip_bf16.h>
#include <cstdint>

using bf16x8 = __attribute__((ext_vector_type(8))) short;
using f32x4  = __attribute__((ext_vector_type(4))) float;
using bf16_t = __hip_bfloat16;

#define DEVI static __device__ __forceinline__

constexpr int kB = 4, kC = 256, kNH = 8, kDh = 32;
constexpr int kVP = 6, kVW = 16, kHP = 32, kHW = 3;
constexpr int kNW = 48, kP = 192, kGRID = 96;
constexpr int kRows = kB * kNW * kP;    // 36864
constexpr int kFF = 1024;
constexpr float kScale = 0.0625f;       // 1/sqrt(C)

DEVI void row_coords(int row, int& b, int& g1, int& g2) {
  int b_  = row / (kNW * kP);
  int rem = row - b_ * (kNW * kP);
  int w = rem / kP;
  int p = rem - w * kP;
  int vw = w / kHW, hw = w - vw * kHW;
  int vp = p >> 5,  hp = p & 31;
  int r  = vp * kVW + vw;
  int cc = hp * kHW + hw;
  g1 = r + 80;  if (g1 >= kGRID) g1 -= kGRID;
  g2 = cc + 93; if (g2 >= kGRID) g2 -= kGRID;
  b = b_;
}

DEVI float bf2f(short s) {
  union { unsigned u; float f; } c;
  c.u = ((unsigned)(unsigned short)s) << 16;
  return c.f;
}
DEVI short f2bf(float f) {
  bf16_t h = __float2bfloat16(f);
  return *reinterpret_cast<short*>(&h);
}

DEVI void gload16(const void* g, void* l) {
  __builtin_amdgcn_global_load_lds(
      (__attribute__((address_space(1))) void*)(uintptr_t)g,
      (__attribute__((address_space(3))) void*)(uintptr_t)l, 16, 0, 0);
}

// asm ds_read_b128: opaque to SIInsertWaitcnts so no compiler vmcnt(0) drain
// attaches to it — makes the counted vmcnt below real (R12: verified -17%).
DEVI bf16x8 ds_read_b128(uint32_t byte_off) {
  bf16x8 v;
  asm volatile("ds_read_b128 %0, %1" : "=v"(v) : "v"(byte_off));
  return v;
}

DEVI float gelu_fast(float v) {
  // sigmoid approximation v*sigma(1.702v) (R18-validated, absmax unchanged).
  return v / (1.f + __expf(-1.702f * v));
}

// ---------------- merged: gather+LN1 (blocks 0..4607) | weight convert
// (blocks 4608..7423). Independent producers for the QKV GEMM; one dispatch
// saves one inter-kernel gap (~1.8us measured).
__global__ __launch_bounds__(256) void k_prep(const float* __restrict__ emb,
    const float* __restrict__ gam, const float* __restrict__ bet,
    bf16_t* __restrict__ Y,
    const float* __restrict__ wq, const float* __restrict__ wk,
    const float* __restrict__ wv, const float* __restrict__ w1,
    const float* __restrict__ w2, bf16_t* __restrict__ W) {
  if (blockIdx.x < kRows / 8) {
    const int wave = threadIdx.x >> 6, lane = threadIdx.x & 63;
    #pragma unroll
    for (int rr = 0; rr < 2; ++rr) {
      const int row = blockIdx.x * 8 + wave * 2 + rr;
      int b, g1, g2; row_coords(row, b, g1, g2);
      const float* src = emb + (((size_t)b * kGRID + g1) * kGRID + g2) * kC;
      float4 x = *reinterpret_cast<const float4*>(src + lane * 4);
      float s  = x.x + x.y + x.z + x.w;
      float sq = x.x*x.x + x.y*x.y + x.z*x.z + x.w*x.w;
      #pragma unroll
      for (int off = 32; off; off >>= 1) { s += __shfl_xor(s, off); sq += __shfl_xor(sq, off); }
      const float mean = s * (1.f / kC);
      const float rstd = rsqrtf(sq * (1.f / kC) - mean * mean + 1e-5f);
      const float4 g4 = *reinterpret_cast<const float4*>(gam + lane * 4);
      const float4 b4 = *reinterpret_cast<const float4*>(bet + lane * 4);
      short4 o;
      o.x = f2bf((x.x - mean) * rstd * g4.x + b4.x);
      o.y = f2bf((x.y - mean) * rstd * g4.y + b4.y);
      o.z = f2bf((x.z - mean) * rstd * g4.z + b4.z);
      o.w = f2bf((x.w - mean) * rstd * g4.w + b4.w);
      *reinterpret_cast<short4*>(Y + (size_t)row * kC + lane * 4) = o;
    }
  } else {
    const int i = (blockIdx.x - kRows / 8) * 256 + threadIdx.x;
    if (i < 196608) {                       // WqkvT: n*256+k
      const int n = i >> 8, k = i & 255;
      const float* src = n < 256 ? wq : (n < 512 ? wk : wv);
      W[i] = __float2bfloat16(src[k * 256 + (n & 255)]);
    } else if (i < 458752) {                // W1T: n*256+k, n<1024
      const int j = i - 196608;
      const int n = j >> 8, k = j & 255;
      W[i] = __float2bfloat16(w1[k * 1024 + n]);
    } else if (i < 720896) {                // W2T: n*1024+k, n<256
      const int j = i - 458752;
      const int n = j >> 10, k = j & 1023;
      W[i] = __float2bfloat16(w2[k * 256 + n]);
    }
  }
}

// ---------------- re-gather + residual + LN2 -> A bf16 (carry), H bf16
__global__ __launch_bounds__(256) void k_ln2(const float* __restrict__ emb,
    const bf16_t* __restrict__ SA,
    const float* __restrict__ gam, const float* __restrict__ bet,
    bf16_t* __restrict__ A, bf16_t* __restrict__ H) {
  const int wave = threadIdx.x >> 6, lane = threadIdx.x & 63;
  #pragma unroll
  for (int rr = 0; rr < 2; ++rr) {
    const int row = blockIdx.x * 8 + wave * 2 + rr;
    int b, g1, g2; row_coords(row, b, g1, g2);
    const float* src = emb + (((size_t)b * kGRID + g1) * kGRID + g2) * kC;
    float4 x = *reinterpret_cast<const float4*>(src + lane * 4);
    short4 sv = *reinterpret_cast<const short4*>(SA + (size_t)row * kC + lane * 4);
    x.x += bf2f(sv.x); x.y += bf2f(sv.y); x.z += bf2f(sv.z); x.w += bf2f(sv.w);
    short4 av;
    av.x = f2bf(x.x); av.y = f2bf(x.y); av.z = f2bf(x.z); av.w = f2bf(x.w);
    *reinterpret_cast<short4*>(A + (size_t)row * kC + lane * 4) = av;
    float s  = x.x + x.y + x.z + x.w;
    float sq = x.x*x.x + x.y*x.y + x.z*x.z + x.w*x.w;
    #pragma unroll
    for (int off = 32; off; off >>= 1) { s += __shfl_xor(s, off); sq += __shfl_xor(sq, off); }
    const float mean = s * (1.f / kC);
    const float rstd = rsqrtf(sq * (1.f / kC) - mean * mean + 1e-5f);
    const float4 g4 = *reinterpret_cast<const float4*>(gam + lane * 4);
    const float4 b4 = *reinterpret_cast<const float4*>(bet + lane * 4);
    short4 o;
    o.x = f2bf((x.x - mean) * rstd * g4.x + b4.x);
    o.y = f2bf((x.y - mean) * rstd * g4.y + b4.y);
    o.z = f2bf((x.z - mean) * rstd * g4.z + b4.z);
    o.w = f2bf((x.w - mean) * rstd * g4.w + b4.w);
    *reinterpret_cast<short4*>(H + (size_t)row * kC + lane * 4) = o;
  }
}

// ---------------- k_gemm8 (R18 best, minus setprio [m190: hurts non-phase-
// split GEMM] and minus the unnecessary EPI2 epilogue barrier [scratch is
// per-wave private]): 128x128 / BK=32 / 4 waves, triple-buffer single-barrier
// depth-2 counted-vmcnt pipeline, swizzle (r>>1)&3 both sides (conflicts 0).
template <int KDIM, int EPI, int GX>
__global__ __launch_bounds__(256, 3) void k_gemm8(
    const bf16_t* __restrict__ Amat, const bf16_t* __restrict__ BT,
    const float* __restrict__ bias0, const float* __restrict__ bias1,
    const float* __restrict__ bias2,
    bf16_t* __restrict__ Obf, const bf16_t* __restrict__ Ares,
    float* __restrict__ Out) {
  __shared__ short sm[24576];            // 48 KB: A[3]|B[3] bufs, then scratch
  bf16_t* As[3] = {(bf16_t*)&sm[0], (bf16_t*)&sm[4096], (bf16_t*)&sm[8192]};
  bf16_t* Bs[3] = {(bf16_t*)&sm[12288], (bf16_t*)&sm[16384], (bf16_t*)&sm[20480]};
  const int tid = threadIdx.x;
  const int wave = tid >> 6, lane = tid & 63;
  const int lr = lane & 15, kg4 = lane >> 4;         // k-group 0..3
  const int nwg = (kRows / 128) * GX;
  const int wg = (blockIdx.x & 7) * (nwg >> 3) + (blockIdx.x >> 3);
  const int m0 = (wg / GX) * 128, n0 = (wg % GX) * 128;
  const int wm = (wave >> 1) * 64, wn = (wave & 1) * 64;
  const int srow = lane >> 2;                        // row within 16-row chunk
  const int scol = ((lane & 3) ^ ((srow >> 1) & 3)) << 3;  // pre-swizzled slot

  auto stage = [&](bf16_t* aDst, bf16_t* bDst, int k0) {
    #pragma unroll
    for (int i = 0; i < 2; ++i) {
      const int c = wave * 2 + i;                    // chunk 0..7
      const int row = c * 16 + srow;
      gload16(Amat + (size_t)(m0 + row) * KDIM + k0 + scol, aDst + c * 512);
      gload16(BT   + (size_t)(n0 + row) * KDIM + k0 + scol, bDst + c * 512);
    }
  };

  const uint32_t aOff[3] = {(uint32_t)(uintptr_t)As[0], (uint32_t)(uintptr_t)As[1],
                            (uint32_t)(uintptr_t)As[2]};
  const uint32_t bOff[3] = {(uint32_t)(uintptr_t)Bs[0], (uint32_t)(uintptr_t)Bs[1],
                            (uint32_t)(uintptr_t)Bs[2]};

  f32x4 acc[4][4] = {};
  auto compute = [&](uint32_t aBase, uint32_t bBase) {
    bf16x8 af[4], bq[4];
    #pragma unroll
    for (int m = 0; m < 4; ++m) {
      const int r = wm + m * 16 + lr;
      af[m] = ds_read_b128(aBase + r * 64 + ((kg4 ^ ((r >> 1) & 3)) << 4));
    }
    #pragma unroll
    for (int n = 0; n < 4; ++n) {
      const int r = wn + n * 16 + lr;
      bq[n] = ds_read_b128(bBase + r * 64 + ((kg4 ^ ((r >> 1) & 3)) << 4));
    }
    asm volatile("s_waitcnt lgkmcnt(0)" ::: "memory");
    __builtin_amdgcn_sched_barrier(0);               // rule #18
    #pragma unroll
    for (int m = 0; m < 4; ++m)
      #pragma unroll
      for (int n = 0; n < 4; ++n)
        acc[m][n] = __builtin_amdgcn_mfma_f32_16x16x32_bf16(af[m], bq[n], acc[m][n], 0, 0, 0);
  };

  stage(As[0], Bs[0], 0);
  if (KDIM > 32) stage(As[1], Bs[1], 32);            // depth-2 prologue
  constexpr int NT = KDIM / 32;
  #pragma unroll
  for (int t = 0; t < NT; ++t) {
    if (t + 1 < NT) {
      asm volatile("s_waitcnt vmcnt(4)" ::: "memory");  // own t-loads landed
    } else {
      asm volatile("s_waitcnt vmcnt(0)" ::: "memory");
    }
    __builtin_amdgcn_sched_barrier(0);
    __builtin_amdgcn_s_barrier();          // all waves: t landed, t-1 computed
    if (t + 2 < NT)
      stage(As[(t + 2) % 3], Bs[(t + 2) % 3], (t + 2) * 32);
    compute(aOff[t % 3], bOff[t % 3]);
  }
  __builtin_amdgcn_s_barrier();            // compute done before LDS reuse
  __builtin_amdgcn_sched_barrier(0);

  if constexpr (EPI == 0 || EPI == 1) {
    short* scr = &sm[wave * 4096];                   // 64x64 bf16, rows 128B
    const int colbase = n0 + wn;
    const float* bp;
    int cb;
    if constexpr (EPI == 0) {
      const int which = colbase >> 8;
      bp = which == 0 ? bias0 : (which == 1 ? bias1 : bias2);
      cb = colbase & 255;
    } else { bp = bias0; cb = colbase; }
    #pragma unroll
    for (int m = 0; m < 4; ++m)
      #pragma unroll
      for (int n = 0; n < 4; ++n)
        #pragma unroll
        for (int r = 0; r < 4; ++r) {
          const int lrow = m * 16 + kg4 * 4 + r;
          const int lcol = n * 16 + lr;
          float v = acc[m][n][r] + bp[cb + lcol];
          if constexpr (EPI == 1) v = gelu_fast(v);
          scr[lrow * 64 + (lcol ^ (((lrow >> 2) & 3) << 4))] = f2bf(v);
        }
    const int rl = lane >> 3, cl = (lane & 7) * 8;   // 8 lanes/row, 16B/lane
    bf16_t* const obase = (EPI == 0)
        ? Obf + (size_t)(colbase >> 8) * kRows * kC
        : Obf;
    const int ld = (EPI == 0) ? kC : kFF;
    #pragma unroll
    for (int p = 0; p < 8; ++p) {
      const int lrow = p * 8 + rl;
      bf16x8 v = *reinterpret_cast<const bf16x8*>(
          &scr[lrow * 64 + (cl ^ (((lrow >> 2) & 3) << 4))]);
      *reinterpret_cast<bf16x8*>(
          obase + (size_t)(m0 + wm + lrow) * ld + cb + cl) = v;
    }
  } else {
    float* scrf = reinterpret_cast<float*>(&sm[wave * 4096]);  // 64x32 f32
    #pragma unroll
    for (int h = 0; h < 2; ++h) {
      #pragma unroll
      for (int m = 0; m < 4; ++m)
        #pragma unroll
        for (int nn = 0; nn < 2; ++nn) {
          const int n = h * 2 + nn;
          #pragma unroll
          for (int r = 0; r < 4; ++r) {
            const int lrow = m * 16 + kg4 * 4 + r;
            const int lcol = nn * 16 + lr;
            scrf[lrow * 32 + (lcol ^ (((lrow >> 2) & 3) << 3))] =
                acc[m][n][r] + bias0[n0 + wn + n * 16 + lr];
          }
        }
      const int rl = lane >> 3, cl = (lane & 7) * 4; // 8 lanes/row, 16B/lane
      #pragma unroll
      for (int p = 0; p < 8; ++p) {
        const int lrow = p * 8 + rl;
        const int row = m0 + wm + lrow;
        const int col = n0 + wn + h * 32 + cl;
        float4 v = *reinterpret_cast<const float4*>(
            &scrf[lrow * 32 + (cl ^ (((lrow >> 2) & 3) << 3))]);
        const short4 a4 = *reinterpret_cast<const short4*>(
            &Ares[(size_t)row * kC + col]);
        v.x += bf2f(a4.x); v.y += bf2f(a4.y);
        v.z += bf2f(a4.z); v.w += bf2f(a4.w);
        int b, g1, g2; row_coords(row, b, g1, g2);
        *reinterpret_cast<float4*>(
            &Out[(((size_t)b * kGRID + g1) * kGRID + g2) * kC + col]) = v;
      }
      // per-wave private scratch: the two halves reuse only this wave's
      // slice, so no barrier is needed between them.
    }
  }
}

// ---------------- MFMA attention (R11-R18, unchanged)
constexpr int kKsPad = 40;
constexpr int kVtPad = 200;
constexpr int kPlPad = 200;
__global__ __launch_bounds__(256) void k_attn(
    const bf16_t* __restrict__ Q, const bf16_t* __restrict__ K,
    const bf16_t* __restrict__ V, const float* __restrict__ pos,
    bf16_t* __restrict__ SA) {
  __shared__ short Ks[kP * kKsPad];
  __shared__ short Vt[kDh * kVtPad];
  __shared__ short Pl[4 * 16 * kPlPad];
  const int bw = blockIdx.x >> 3, h = blockIdx.x & 7;
  const int rowbase = bw * kP, colbase = h * kDh;
  const int tid = threadIdx.x, wave = tid >> 6, lane = tid & 63;
  const int lr = lane & 15, kg = lane >> 4;
  const int wq0 = wave * 48;
  const float* pb = pos + (size_t)h * kP * kP;

  #pragma unroll
  for (int i = 0; i < 3; ++i) {
    const int c = tid + i * 256;
    const int row = c >> 2, dch = (c & 3) * 8;
    const size_t gbase = (size_t)(rowbase + row) * kC + colbase + dch;
    bf16x8 kv = *reinterpret_cast<const bf16x8*>(K + gbase);
    *reinterpret_cast<bf16x8*>(&Ks[row * kKsPad + dch]) = kv;
    bf16x8 vv = *reinterpret_cast<const bf16x8*>(V + gbase);
    #pragma unroll
    for (int e = 0; e < 8; ++e) Vt[(dch + e) * kVtPad + row] = vv[e];
  }
  __syncthreads();

  for (int m = 0; m < 3; ++m) {
    const int rbase = wq0 + m * 16;
    bf16x8 aq = *reinterpret_cast<const bf16x8*>(
        Q + (size_t)(rowbase + rbase + lr) * kC + colbase + kg * 8);
    f32x4 s[12];
    #pragma unroll
    for (int n = 0; n < 12; ++n) {
      bf16x8 bk = *reinterpret_cast<const bf16x8*>(&Ks[(n * 16 + lr) * kKsPad + kg * 8]);
      s[n] = __builtin_amdgcn_mfma_f32_16x16x32_bf16(aq, bk, (f32x4){0.f, 0.f, 0.f, 0.f}, 0, 0, 0);
    }
    float mx[4] = {-1e30f, -1e30f, -1e30f, -1e30f};
    #pragma unroll
    for (int n = 0; n < 12; ++n) {
      #pragma unroll
      for (int r = 0; r < 4; ++r) {
        const float lg = fmaf(s[n][r], kScale,
                              pb[(size_t)(rbase + kg * 4 + r) * kP + n * 16 + lr]);
        s[n][r] = lg;
        mx[r] = fmaxf(mx[r], lg);
      }
    }
    #pragma unroll
    for (int r = 0; r < 4; ++r)
      #pragma unroll
      for (int off = 8; off; off >>= 1) mx[r] = fmaxf(mx[r], __shfl_xor(mx[r], off));
    float sm4[4] = {0.f, 0.f, 0.f, 0.f};
    #pragma unroll
    for (int n = 0; n < 12; ++n)
      #pragma unroll
      for (int r = 0; r < 4; ++r) {
        const float e = __expf(s[n][r] - mx[r]);
        s[n][r] = e;
        sm4[r] += e;
      }
    #pragma unroll
    for (int r = 0; r < 4; ++r) {
      #pragma unroll
      for (int off = 8; off; off >>= 1) sm4[r] += __shfl_xor(sm4[r], off);
      sm4[r] = 1.f / sm4[r];
    }
    #pragma unroll
    for (int n = 0; n < 12; ++n)
      #pragma unroll
      for (int r = 0; r < 4; ++r)
        Pl[(wave * 16 + kg * 4 + r) * kPlPad + n * 16 + lr] = f2bf(s[n][r] * sm4[r]);
    f32x4 o0 = {0.f, 0.f, 0.f, 0.f}, o1 = {0.f, 0.f, 0.f, 0.f};
    #pragma unroll
    for (int kk = 0; kk < 6; ++kk) {
      bf16x8 ap = *reinterpret_cast<const bf16x8*>(&Pl[(wave * 16 + lr) * kPlPad + kk * 32 + kg * 8]);
      bf16x8 b0 = *reinterpret_cast<const bf16x8*>(&Vt[lr * kVtPad + kk * 32 + kg * 8]);
      bf16x8 b1 = *reinterpret_cast<const bf16x8*>(&Vt[(16 + lr) * kVtPad + kk * 32 + kg * 8]);
      o0 = __builtin_amdgcn_mfma_f32_16x16x32_bf16(ap, b0, o0, 0, 0, 0);
      o1 = __builtin_amdgcn_mfma_f32_16x16x32_bf16(ap, b1, o1, 0, 0, 0);
    }
    short* scr2 = &Pl[wave * 16 * kPlPad];
    #pragma unroll
    for (int r = 0; r < 4; ++r) {
      scr2[(kg * 4 + r) * 32 + lr]      = f2bf(o0[r]);
      scr2[(kg * 4 + r) * 32 + 16 + lr] = f2bf(o1[r]);
    }
    {
      const int rrow = lane >> 2, c0 = (lane & 3) * 8;
      bf16x8 v = *reinterpret_cast<const bf16x8*>(&scr2[rrow * 32 + c0]);
      *reinterpret_cast<bf16x8*>(
          SA + (size_t)(rowbase + rbase + rrow) * kC + colbase + c0) = v;
    }
  }
}

extern "C" void kernel_launch(void* const* d_in, const int* in_sizes, int n_in,
                              void* d_out, int out_size, void* d_ws, size_t ws_size,
                              hipStream_t stream) {
  const float* emb  = (const float*)d_in[0];
  const float* ln1g = (const float*)d_in[1];
  const float* ln1b = (const float*)d_in[2];
  const float* wq   = (const float*)d_in[3];
  const float* bq   = (const float*)d_in[4];
  const float* wk   = (const float*)d_in[5];
  const float* bk   = (const float*)d_in[6];
  const float* wv   = (const float*)d_in[7];
  const float* bv   = (const float*)d_in[8];
  const float* pos  = (const float*)d_in[9];
  const float* ln2g = (const float*)d_in[10];
  const float* ln2b = (const float*)d_in[11];
  const float* w1   = (const float*)d_in[12];
  const float* b1   = (const float*)d_in[13];
  const float* w2   = (const float*)d_in[14];
  const float* b2   = (const float*)d_in[15];

  char* ws = (char*)d_ws;
  const size_t nYb = (size_t)kRows * kC * 2;               // 18,874,368 B
  bf16_t* Y    = (bf16_t*)(ws);
  bf16_t* Qb   = (bf16_t*)(ws + nYb);                      // Q,K,V consecutive
  bf16_t* SAb  = (bf16_t*)(ws + nYb * 4);
  bf16_t* Abuf = (bf16_t*)(ws + nYb * 5);                  // bf16 carry
  bf16_t* H    = (bf16_t*)(ws + nYb * 5 + (size_t)kRows * kC * 4);
  bf16_t* G    = (bf16_t*)(ws);                            // alias dead Y/Q/K/V
  bf16_t* W    = (bf16_t*)(ws + nYb * 5 + (size_t)kRows * kC * 4 + nYb);
  bf16_t* WqkvT = W;
  bf16_t* W1T   = W + 768 * 256;
  bf16_t* W2T   = W1T + 1024 * 256;

  k_prep<<<kRows / 8 + 2816, 256, 0, stream>>>(
      emb, ln1g, ln1b, Y, wq, wk, wv, w1, w2, W);
  k_gemm8<256, 0, 6><<<(kRows / 128) * 6, 256, 0, stream>>>(
      Y, WqkvT, bq, bk, bv, Qb, nullptr, nullptr);
  k_attn<<<kB * kNW * kNH, 256, 0, stream>>>(
      Qb, Qb + (size_t)kRows * kC, Qb + 2 * (size_t)kRows * kC, pos, SAb);
  k_ln2<<<kRows / 8, 256, 0, stream>>>(emb, SAb, ln2g, ln2b, Abuf, H);
  k_gemm8<256, 1, 8><<<(kRows / 128) * 8, 256, 0, stream>>>(
      H, W1T, b1, nullptr, nullptr, G, nullptr, nullptr);
  k_gemm8<1024, 2, 2><<<(kRows / 128) * 2, 256, 0, stream>>>(
      G, W2T, b2, nullptr, nullptr, nullptr, Abuf, (float*)d_out);
}

// Round 20
// 164.216 us; speedup vs baseline: 1.1108x; 1.0245x over previous
//
#include <hip/hip_runtime.h>
#include <hip/hip_bf16.h>
#include <cstdint>

using bf16x8 = __attribute__((ext_vector_type(8))) short;
using f32x4  = __attribute__((ext_vector_type(4))) float;
using bf16_t = __hip_bfloat16;

#define DEVI static __device__ __forceinline__

constexpr int kB = 4, kC = 256, kNH = 8, kDh = 32;
constexpr int kVP = 6, kVW = 16, kHP = 32, kHW = 3;
constexpr int kNW = 48, kP = 192, kGRID = 96;
constexpr int kRows = kB * kNW * kP;    // 36864
constexpr int kFF = 1024;
constexpr float kScale = 0.0625f;       // 1/sqrt(C)

DEVI void row_coords(int row, int& b, int& g1, int& g2) {
  int b_  = row / (kNW * kP);
  int rem = row - b_ * (kNW * kP);
  int w = rem / kP;
  int p = rem - w * kP;
  int vw = w / kHW, hw = w - vw * kHW;
  int vp = p >> 5,  hp = p & 31;
  int r  = vp * kVW + vw;
  int cc = hp * kHW + hw;
  g1 = r + 80;  if (g1 >= kGRID) g1 -= kGRID;
  g2 = cc + 93; if (g2 >= kGRID) g2 -= kGRID;
  b = b_;
}

DEVI float bf2f(short s) {
  union { unsigned u; float f; } c;
  c.u = ((unsigned)(unsigned short)s) << 16;
  return c.f;
}
DEVI short f2bf(float f) {
  bf16_t h = __float2bfloat16(f);
  return *reinterpret_cast<short*>(&h);
}

DEVI void gload16(const void* g, void* l) {
  __builtin_amdgcn_global_load_lds(
      (__attribute__((address_space(1))) void*)(uintptr_t)g,
      (__attribute__((address_space(3))) void*)(uintptr_t)l, 16, 0, 0);
}

// asm ds_read_b128: opaque to SIInsertWaitcnts so no compiler vmcnt(0) drain
// attaches to it — makes the counted vmcnt below real (R12: verified -17%).
DEVI bf16x8 ds_read_b128(uint32_t byte_off) {
  bf16x8 v;
  asm volatile("ds_read_b128 %0, %1" : "=v"(v) : "v"(byte_off));
  return v;
}

DEVI float gelu_fast(float v) {
  // sigmoid approximation v*sigma(1.702v) (R18-validated, absmax unchanged).
  return v / (1.f + __expf(-1.702f * v));
}

// ---------------- merged: gather+LN1 (blocks 0..4607) | weight convert
__global__ __launch_bounds__(256) void k_prep(const float* __restrict__ emb,
    const float* __restrict__ gam, const float* __restrict__ bet,
    bf16_t* __restrict__ Y,
    const float* __restrict__ wq, const float* __restrict__ wk,
    const float* __restrict__ wv, const float* __restrict__ w1,
    const float* __restrict__ w2, bf16_t* __restrict__ W) {
  if (blockIdx.x < kRows / 8) {
    const int wave = threadIdx.x >> 6, lane = threadIdx.x & 63;
    #pragma unroll
    for (int rr = 0; rr < 2; ++rr) {
      const int row = blockIdx.x * 8 + wave * 2 + rr;
      int b, g1, g2; row_coords(row, b, g1, g2);
      const float* src = emb + (((size_t)b * kGRID + g1) * kGRID + g2) * kC;
      float4 x = *reinterpret_cast<const float4*>(src + lane * 4);
      float s  = x.x + x.y + x.z + x.w;
      float sq = x.x*x.x + x.y*x.y + x.z*x.z + x.w*x.w;
      #pragma unroll
      for (int off = 32; off; off >>= 1) { s += __shfl_xor(s, off); sq += __shfl_xor(sq, off); }
      const float mean = s * (1.f / kC);
      const float rstd = rsqrtf(sq * (1.f / kC) - mean * mean + 1e-5f);
      const float4 g4 = *reinterpret_cast<const float4*>(gam + lane * 4);
      const float4 b4 = *reinterpret_cast<const float4*>(bet + lane * 4);
      short4 o;
      o.x = f2bf((x.x - mean) * rstd * g4.x + b4.x);
      o.y = f2bf((x.y - mean) * rstd * g4.y + b4.y);
      o.z = f2bf((x.z - mean) * rstd * g4.z + b4.z);
      o.w = f2bf((x.w - mean) * rstd * g4.w + b4.w);
      *reinterpret_cast<short4*>(Y + (size_t)row * kC + lane * 4) = o;
    }
  } else {
    const int i = (blockIdx.x - kRows / 8) * 256 + threadIdx.x;
    if (i < 196608) {                       // WqkvT: n*256+k
      const int n = i >> 8, k = i & 255;
      const float* src = n < 256 ? wq : (n < 512 ? wk : wv);
      W[i] = __float2bfloat16(src[k * 256 + (n & 255)]);
    } else if (i < 458752) {                // W1T: n*256+k, n<1024
      const int j = i - 196608;
      const int n = j >> 8, k = j & 255;
      W[i] = __float2bfloat16(w1[k * 1024 + n]);
    } else if (i < 720896) {                // W2T: n*1024+k, n<256
      const int j = i - 458752;
      const int n = j >> 10, k = j & 1023;
      W[i] = __float2bfloat16(w2[k * 256 + n]);
    }
  }
}

// ---------------- re-gather + residual + LN2 -> A bf16 (carry), H bf16
__global__ __launch_bounds__(256) void k_ln2(const float* __restrict__ emb,
    const bf16_t* __restrict__ SA,
    const float* __restrict__ gam, const float* __restrict__ bet,
    bf16_t* __restrict__ A, bf16_t* __restrict__ H) {
  const int wave = threadIdx.x >> 6, lane = threadIdx.x & 63;
  #pragma unroll
  for (int rr = 0; rr < 2; ++rr) {
    const int row = blockIdx.x * 8 + wave * 2 + rr;
    int b, g1, g2; row_coords(row, b, g1, g2);
    const float* src = emb + (((size_t)b * kGRID + g1) * kGRID + g2) * kC;
    float4 x = *reinterpret_cast<const float4*>(src + lane * 4);
    short4 sv = *reinterpret_cast<const short4*>(SA + (size_t)row * kC + lane * 4);
    x.x += bf2f(sv.x); x.y += bf2f(sv.y); x.z += bf2f(sv.z); x.w += bf2f(sv.w);
    short4 av;
    av.x = f2bf(x.x); av.y = f2bf(x.y); av.z = f2bf(x.z); av.w = f2bf(x.w);
    *reinterpret_cast<short4*>(A + (size_t)row * kC + lane * 4) = av;
    float s  = x.x + x.y + x.z + x.w;
    float sq = x.x*x.x + x.y*x.y + x.z*x.z + x.w*x.w;
    #pragma unroll
    for (int off = 32; off; off >>= 1) { s += __shfl_xor(s, off); sq += __shfl_xor(sq, off); }
    const float mean = s * (1.f / kC);
    const float rstd = rsqrtf(sq * (1.f / kC) - mean * mean + 1e-5f);
    const float4 g4 = *reinterpret_cast<const float4*>(gam + lane * 4);
    const float4 b4 = *reinterpret_cast<const float4*>(bet + lane * 4);
    short4 o;
    o.x = f2bf((x.x - mean) * rstd * g4.x + b4.x);
    o.y = f2bf((x.y - mean) * rstd * g4.y + b4.y);
    o.z = f2bf((x.z - mean) * rstd * g4.z + b4.z);
    o.w = f2bf((x.w - mean) * rstd * g4.w + b4.w);
    *reinterpret_cast<short4*>(H + (size_t)row * kC + lane * 4) = o;
  }
}

// ---------------- k_gemm8 (R19 best): 128x128 / BK=32 / 4 waves,
// triple-buffer single-barrier depth-2 counted-vmcnt pipeline, swizzle
// (r>>1)&3 both sides (conflicts 0), no setprio (m190).
template <int KDIM, int EPI, int GX>
__global__ __launch_bounds__(256, 3) void k_gemm8(
    const bf16_t* __restrict__ Amat, const bf16_t* __restrict__ BT,
    const float* __restrict__ bias0, const float* __restrict__ bias1,
    const float* __restrict__ bias2,
    bf16_t* __restrict__ Obf, const bf16_t* __restrict__ Ares,
    float* __restrict__ Out) {
  __shared__ short sm[24576];            // 48 KB: A[3]|B[3] bufs, then scratch
  bf16_t* As[3] = {(bf16_t*)&sm[0], (bf16_t*)&sm[4096], (bf16_t*)&sm[8192]};
  bf16_t* Bs[3] = {(bf16_t*)&sm[12288], (bf16_t*)&sm[16384], (bf16_t*)&sm[20480]};
  const int tid = threadIdx.x;
  const int wave = tid >> 6, lane = tid & 63;
  const int lr = lane & 15, kg4 = lane >> 4;         // k-group 0..3
  const int nwg = (kRows / 128) * GX;
  const int wg = (blockIdx.x & 7) * (nwg >> 3) + (blockIdx.x >> 3);
  const int m0 = (wg / GX) * 128, n0 = (wg % GX) * 128;
  const int wm = (wave >> 1) * 64, wn = (wave & 1) * 64;
  const int srow = lane >> 2;                        // row within 16-row chunk
  const int scol = ((lane & 3) ^ ((srow >> 1) & 3)) << 3;  // pre-swizzled slot

  auto stage = [&](bf16_t* aDst, bf16_t* bDst, int k0) {
    #pragma unroll
    for (int i = 0; i < 2; ++i) {
      const int c = wave * 2 + i;                    // chunk 0..7
      const int row = c * 16 + srow;
      gload16(Amat + (size_t)(m0 + row) * KDIM + k0 + scol, aDst + c * 512);
      gload16(BT   + (size_t)(n0 + row) * KDIM + k0 + scol, bDst + c * 512);
    }
  };

  const uint32_t aOff[3] = {(uint32_t)(uintptr_t)As[0], (uint32_t)(uintptr_t)As[1],
                            (uint32_t)(uintptr_t)As[2]};
  const uint32_t bOff[3] = {(uint32_t)(uintptr_t)Bs[0], (uint32_t)(uintptr_t)Bs[1],
                            (uint32_t)(uintptr_t)Bs[2]};

  f32x4 acc[4][4] = {};
  auto compute = [&](uint32_t aBase, uint32_t bBase) {
    bf16x8 af[4], bq[4];
    #pragma unroll
    for (int m = 0; m < 4; ++m) {
      const int r = wm + m * 16 + lr;
      af[m] = ds_read_b128(aBase + r * 64 + ((kg4 ^ ((r >> 1) & 3)) << 4));
    }
    #pragma unroll
    for (int n = 0; n < 4; ++n) {
      const int r = wn + n * 16 + lr;
      bq[n] = ds_read_b128(bBase + r * 64 + ((kg4 ^ ((r >> 1) & 3)) << 4));
    }
    asm volatile("s_waitcnt lgkmcnt(0)" ::: "memory");
    __builtin_amdgcn_sched_barrier(0);               // rule #18
    #pragma unroll
    for (int m = 0; m < 4; ++m)
      #pragma unroll
      for (int n = 0; n < 4; ++n)
        acc[m][n] = __builtin_amdgcn_mfma_f32_16x16x32_bf16(af[m], bq[n], acc[m][n], 0, 0, 0);
  };

  stage(As[0], Bs[0], 0);
  if (KDIM > 32) stage(As[1], Bs[1], 32);            // depth-2 prologue
  constexpr int NT = KDIM / 32;
  #pragma unroll
  for (int t = 0; t < NT; ++t) {
    if (t + 1 < NT) {
      asm volatile("s_waitcnt vmcnt(4)" ::: "memory");  // own t-loads landed
    } else {
      asm volatile("s_waitcnt vmcnt(0)" ::: "memory");
    }
    __builtin_amdgcn_sched_barrier(0);
    __builtin_amdgcn_s_barrier();          // all waves: t landed, t-1 computed
    if (t + 2 < NT)
      stage(As[(t + 2) % 3], Bs[(t + 2) % 3], (t + 2) * 32);
    compute(aOff[t % 3], bOff[t % 3]);
  }
  __builtin_amdgcn_s_barrier();            // compute done before LDS reuse
  __builtin_amdgcn_sched_barrier(0);

  if constexpr (EPI == 0 || EPI == 1) {
    short* scr = &sm[wave * 4096];                   // 64x64 bf16, rows 128B
    const int colbase = n0 + wn;
    const float* bp;
    int cb;
    if constexpr (EPI == 0) {
      const int which = colbase >> 8;
      bp = which == 0 ? bias0 : (which == 1 ? bias1 : bias2);
      cb = colbase & 255;
    } else { bp = bias0; cb = colbase; }
    #pragma unroll
    for (int m = 0; m < 4; ++m)
      #pragma unroll
      for (int n = 0; n < 4; ++n)
        #pragma unroll
        for (int r = 0; r < 4; ++r) {
          const int lrow = m * 16 + kg4 * 4 + r;
          const int lcol = n * 16 + lr;
          float v = acc[m][n][r] + bp[cb + lcol];
          if constexpr (EPI == 1) v = gelu_fast(v);
          scr[lrow * 64 + (lcol ^ (((lrow >> 2) & 3) << 4))] = f2bf(v);
        }
    const int rl = lane >> 3, cl = (lane & 7) * 8;   // 8 lanes/row, 16B/lane
    bf16_t* const obase = (EPI == 0)
        ? Obf + (size_t)(colbase >> 8) * kRows * kC
        : Obf;
    const int ld = (EPI == 0) ? kC : kFF;
    #pragma unroll
    for (int p = 0; p < 8; ++p) {
      const int lrow = p * 8 + rl;
      bf16x8 v = *reinterpret_cast<const bf16x8*>(
          &scr[lrow * 64 + (cl ^ (((lrow >> 2) & 3) << 4))]);
      *reinterpret_cast<bf16x8*>(
          obase + (size_t)(m0 + wm + lrow) * ld + cb + cl) = v;
    }
  } else {
    float* scrf = reinterpret_cast<float*>(&sm[wave * 4096]);  // 64x32 f32
    #pragma unroll
    for (int h = 0; h < 2; ++h) {
      #pragma unroll
      for (int m = 0; m < 4; ++m)
        #pragma unroll
        for (int nn = 0; nn < 2; ++nn) {
          const int n = h * 2 + nn;
          #pragma unroll
          for (int r = 0; r < 4; ++r) {
            const int lrow = m * 16 + kg4 * 4 + r;
            const int lcol = nn * 16 + lr;
            scrf[lrow * 32 + (lcol ^ (((lrow >> 2) & 3) << 3))] =
                acc[m][n][r] + bias0[n0 + wn + n * 16 + lr];
          }
        }
      const int rl = lane >> 3, cl = (lane & 7) * 4; // 8 lanes/row, 16B/lane
      #pragma unroll
      for (int p = 0; p < 8; ++p) {
        const int lrow = p * 8 + rl;
        const int row = m0 + wm + lrow;
        const int col = n0 + wn + h * 32 + cl;
        float4 v = *reinterpret_cast<const float4*>(
            &scrf[lrow * 32 + (cl ^ (((lrow >> 2) & 3) << 3))]);
        const short4 a4 = *reinterpret_cast<const short4*>(
            &Ares[(size_t)row * kC + col]);
        v.x += bf2f(a4.x); v.y += bf2f(a4.y);
        v.z += bf2f(a4.z); v.w += bf2f(a4.w);
        int b, g1, g2; row_coords(row, b, g1, g2);
        *reinterpret_cast<float4*>(
            &Out[(((size_t)b * kGRID + g1) * kGRID + g2) * kC + col]) = v;
      }
      // per-wave private scratch: no barrier needed between halves.
    }
  }
}

// ---------------- MFMA attention (R11-R19 structure; NEW: T1 XCD swizzle so
// all 8 heads of one window run on the SAME XCD -> shared K/V cache lines
// (heads read adjacent 64B segments of the same 512B rows) become L2-local.
// Mapping: xcd=i&7, j=i>>3; bw=xcd*24+(j>>3), h=j&7. Bijective (1536=8*24*8);
// all heads of a window have indices congruent mod 8.
constexpr int kKsPad = 40;
constexpr int kVtPad = 200;
constexpr int kPlPad = 200;
__global__ __launch_bounds__(256) void k_attn(
    const bf16_t* __restrict__ Q, const bf16_t* __restrict__ K,
    const bf16_t* __restrict__ V, const float* __restrict__ pos,
    bf16_t* __restrict__ SA) {
  __shared__ short Ks[kP * kKsPad];
  __shared__ short Vt[kDh * kVtPad];
  __shared__ short Pl[4 * 16 * kPlPad];
  const int i = blockIdx.x;
  const int j = i >> 3;
  const int bw = (i & 7) * 24 + (j >> 3), h = j & 7;
  const int rowbase = bw * kP, colbase = h * kDh;
  const int tid = threadIdx.x, wave = tid >> 6, lane = tid & 63;
  const int lr = lane & 15, kg = lane >> 4;
  const int wq0 = wave * 48;
  const float* pb = pos + (size_t)h * kP * kP;

  #pragma unroll
  for (int ii = 0; ii < 3; ++ii) {
    const int c = tid + ii * 256;
    const int row = c >> 2, dch = (c & 3) * 8;
    const size_t gbase = (size_t)(rowbase + row) * kC + colbase + dch;
    bf16x8 kv = *reinterpret_cast<const bf16x8*>(K + gbase);
    *reinterpret_cast<bf16x8*>(&Ks[row * kKsPad + dch]) = kv;
    bf16x8 vv = *reinterpret_cast<const bf16x8*>(V + gbase);
    #pragma unroll
    for (int e = 0; e < 8; ++e) Vt[(dch + e) * kVtPad + row] = vv[e];
  }
  __syncthreads();

  for (int m = 0; m < 3; ++m) {
    const int rbase = wq0 + m * 16;
    bf16x8 aq = *reinterpret_cast<const bf16x8*>(
        Q + (size_t)(rowbase + rbase + lr) * kC + colbase + kg * 8);
    f32x4 s[12];
    #pragma unroll
    for (int n = 0; n < 12; ++n) {
      bf16x8 bk = *reinterpret_cast<const bf16x8*>(&Ks[(n * 16 + lr) * kKsPad + kg * 8]);
      s[n] = __builtin_amdgcn_mfma_f32_16x16x32_bf16(aq, bk, (f32x4){0.f, 0.f, 0.f, 0.f}, 0, 0, 0);
    }
    float mx[4] = {-1e30f, -1e30f, -1e30f, -1e30f};
    #pragma unroll
    for (int n = 0; n < 12; ++n) {
      #pragma unroll
      for (int r = 0; r < 4; ++r) {
        const float lg = fmaf(s[n][r], kScale,
                              pb[(size_t)(rbase + kg * 4 + r) * kP + n * 16 + lr]);
        s[n][r] = lg;
        mx[r] = fmaxf(mx[r], lg);
      }
    }
    #pragma unroll
    for (int r = 0; r < 4; ++r)
      #pragma unroll
      for (int off = 8; off; off >>= 1) mx[r] = fmaxf(mx[r], __shfl_xor(mx[r], off));
    float sm4[4] = {0.f, 0.f, 0.f, 0.f};
    #pragma unroll
    for (int n = 0; n < 12; ++n)
      #pragma unroll
      for (int r = 0; r < 4; ++r) {
        const float e = __expf(s[n][r] - mx[r]);
        s[n][r] = e;
        sm4[r] += e;
      }
    #pragma unroll
    for (int r = 0; r < 4; ++r) {
      #pragma unroll
      for (int off = 8; off; off >>= 1) sm4[r] += __shfl_xor(sm4[r], off);
      sm4[r] = 1.f / sm4[r];
    }
    #pragma unroll
    for (int n = 0; n < 12; ++n)
      #pragma unroll
      for (int r = 0; r < 4; ++r)
        Pl[(wave * 16 + kg * 4 + r) * kPlPad + n * 16 + lr] = f2bf(s[n][r] * sm4[r]);
    f32x4 o0 = {0.f, 0.f, 0.f, 0.f}, o1 = {0.f, 0.f, 0.f, 0.f};
    #pragma unroll
    for (int kk = 0; kk < 6; ++kk) {
      bf16x8 ap = *reinterpret_cast<const bf16x8*>(&Pl[(wave * 16 + lr) * kPlPad + kk * 32 + kg * 8]);
      bf16x8 b0 = *reinterpret_cast<const bf16x8*>(&Vt[lr * kVtPad + kk * 32 + kg * 8]);
      bf16x8 b1 = *reinterpret_cast<const bf16x8*>(&Vt[(16 + lr) * kVtPad + kk * 32 + kg * 8]);
      o0 = __builtin_amdgcn_mfma_f32_16x16x32_bf16(ap, b0, o0, 0, 0, 0);
      o1 = __builtin_amdgcn_mfma_f32_16x16x32_bf16(ap, b1, o1, 0, 0, 0);
    }
    short* scr2 = &Pl[wave * 16 * kPlPad];
    #pragma unroll
    for (int r = 0; r < 4; ++r) {
      scr2[(kg * 4 + r) * 32 + lr]      = f2bf(o0[r]);
      scr2[(kg * 4 + r) * 32 + 16 + lr] = f2bf(o1[r]);
    }
    {
      const int rrow = lane >> 2, c0 = (lane & 3) * 8;
      bf16x8 v = *reinterpret_cast<const bf16x8*>(&scr2[rrow * 32 + c0]);
      *reinterpret_cast<bf16x8*>(
          SA + (size_t)(rowbase + rbase + rrow) * kC + colbase + c0) = v;
    }
  }
}

extern "C" void kernel_launch(void* const* d_in, const int* in_sizes, int n_in,
                              void* d_out, int out_size, void* d_ws, size_t ws_size,
                              hipStream_t stream) {
  const float* emb  = (const float*)d_in[0];
  const float* ln1g = (const float*)d_in[1];
  const float* ln1b = (const float*)d_in[2];
  const float* wq   = (const float*)d_in[3];
  const float* bq   = (const float*)d_in[4];
  const float* wk   = (const float*)d_in[5];
  const float* bk   = (const float*)d_in[6];
  const float* wv   = (const float*)d_in[7];
  const float* bv   = (const float*)d_in[8];
  const float* pos  = (const float*)d_in[9];
  const float* ln2g = (const float*)d_in[10];
  const float* ln2b = (const float*)d_in[11];
  const float* w1   = (const float*)d_in[12];
  const float* b1   = (const float*)d_in[13];
  const float* w2   = (const float*)d_in[14];
  const float* b2   = (const float*)d_in[15];

  char* ws = (char*)d_ws;
  const size_t nYb = (size_t)kRows * kC * 2;               // 18,874,368 B
  bf16_t* Y    = (bf16_t*)(ws);
  bf16_t* Qb   = (bf16_t*)(ws + nYb);                      // Q,K,V consecutive
  bf16_t* SAb  = (bf16_t*)(ws + nYb * 4);
  bf16_t* Abuf = (bf16_t*)(ws + nYb * 5);                  // bf16 carry
  bf16_t* H    = (bf16_t*)(ws + nYb * 5 + (size_t)kRows * kC * 4);
  bf16_t* G    = (bf16_t*)(ws);                            // alias dead Y/Q/K/V
  bf16_t* W    = (bf16_t*)(ws + nYb * 5 + (size_t)kRows * kC * 4 + nYb);
  bf16_t* WqkvT = W;
  bf16_t* W1T   = W + 768 * 256;
  bf16_t* W2T   = W1T + 1024 * 256;

  k_prep<<<kRows / 8 + 2816, 256, 0, stream>>>(
      emb, ln1g, ln1b, Y, wq, wk, wv, w1, w2, W);
  k_gemm8<256, 0, 6><<<(kRows / 128) * 6, 256, 0, stream>>>(
      Y, WqkvT, bq, bk, bv, Qb, nullptr, nullptr);
  k_attn<<<kB * kNW * kNH, 256, 0, stream>>>(
      Qb, Qb + (size_t)kRows * kC, Qb + 2 * (size_t)kRows * kC, pos, SAb);
  k_ln2<<<kRows / 8, 256, 0, stream>>>(emb, SAb, ln2g, ln2b, Abuf, H);
  k_gemm8<256, 1, 8><<<(kRows / 128) * 8, 256, 0, stream>>>(
      H, W1T, b1, nullptr, nullptr, G, nullptr, nullptr);
  k_gemm8<1024, 2, 2><<<(kRows / 128) * 2, 256, 0, stream>>>(
      G, W2T, b2, nullptr, nullptr, nullptr, Abuf, (float*)d_out);
}